// Round 3
// baseline (161.198 us; speedup 1.0000x reference)
//
#include <hip/hip_runtime.h>

// LocalLinear: out[b,j] = sum_{e: rows[e]==j} x[b, cols[e]] * w[e] + bias[j]
// B=32, N_IN=65536, N_OUT=65536, NNZ=2097152 (rows sorted, int32).
// Round-3 bisect build: NO cross-lane ops in compute. Half-wave owns one j.

// ---------------- Kernel 1: transpose x (B x N_IN) -> xT (N_IN x 32) ----------------
__global__ __launch_bounds__(256) void transpose_x_kernel(
    const float* __restrict__ x, float* __restrict__ xT, int n_in) {
  __shared__ float t[32][65];
  int c0 = blockIdx.x * 64;
  for (int idx = threadIdx.x; idx < 32 * 64; idx += 256) {
    int b = idx >> 6, cl = idx & 63;
    int c = c0 + cl;
    t[b][cl] = (c < n_in) ? x[(size_t)b * n_in + c] : 0.0f;
  }
  __syncthreads();
  for (int idx = threadIdx.x; idx < 64 * 32; idx += 256) {
    int cl = idx >> 5, b = idx & 31;
    int c = c0 + cl;
    if (c < n_in) xT[(size_t)c * 32 + b] = t[b][cl];
  }
}

// ---------------- Kernel 2: main gather/accumulate (no shfl, no row_ptr) ----------------
// Each half-wave (32 lanes = 32 batches) owns one output j at a time.
// FAST: xsrc = xT (n_in x 32), coalesced gather.  !FAST: xsrc = x (B x n_in), strided.
template <bool FAST>
__global__ __launch_bounds__(256) void ll_main_kernel(
    const float* __restrict__ xsrc,
    const float* __restrict__ wgt,
    const float* __restrict__ bias,
    const int* __restrict__ rows,
    const int* __restrict__ cols,
    float* __restrict__ out,
    int n_in, int n_out, int nnz) {
  __shared__ float tile[32][33];
  int tid = threadIdx.x;
  int b = tid & 31;        // batch index (lane within half-wave)
  int hw = tid >> 5;       // half-wave id 0..7
  int jb = blockIdx.x * 32;

  for (int jq = 0; jq < 4; ++jq) {
    int jl = hw * 4 + jq;
    int j = jb + jl;
    float acc = 0.0f;
    if (j < n_out) {
      // binary search: s = first e with rows[e] >= j; e = first e with rows[e] > j
      int lo = 0, hi = nnz;
      while (lo < hi) { int m = (lo + hi) >> 1; if (rows[m] < j) lo = m + 1; else hi = m; }
      int s = lo;
      hi = nnz;
      while (lo < hi) { int m = (lo + hi) >> 1; if (rows[m] <= j) lo = m + 1; else hi = m; }
      int e = lo;
      for (int t = s; t < e; ++t) {
        int c = cols[t];       // half-wave-uniform load
        float w = wgt[t];      // half-wave-uniform load
        float xv = FAST ? xsrc[(size_t)c * 32 + b]      // coalesced 128B per half-wave
                        : xsrc[(size_t)b * n_in + c];   // strided fallback
        acc = fmaf(w, xv, acc);
      }
    }
    tile[b][jl] = acc;
  }
  __syncthreads();
  // coalesced write of the 32x32 output tile (+bias)
  for (int idx = tid; idx < 32 * 32; idx += 256) {
    int bb = idx >> 5, jl = idx & 31;
    int j = jb + jl;
    if (j < n_out) out[(size_t)bb * n_out + j] = tile[bb][jl] + bias[j];
  }
}

// ---------------- Kernel 3: last-resort naive (B != 32) ----------------
__global__ __launch_bounds__(256) void ll_naive_kernel(
    const float* __restrict__ x,
    const float* __restrict__ wgt,
    const float* __restrict__ bias,
    const int* __restrict__ rows,
    const int* __restrict__ cols,
    float* __restrict__ out,
    int n_in, int n_out, int nnz, int B) {
  int idx = blockIdx.x * blockDim.x + threadIdx.x;
  if (idx >= n_out * B) return;
  int j = idx % n_out;
  int b = idx / n_out;
  int lo = 0, hi = nnz;
  while (lo < hi) { int m = (lo + hi) >> 1; if (rows[m] < j) lo = m + 1; else hi = m; }
  int s = lo;
  hi = nnz;
  while (lo < hi) { int m = (lo + hi) >> 1; if (rows[m] <= j) lo = m + 1; else hi = m; }
  int e = lo;
  float acc = 0.0f;
  for (int t = s; t < e; ++t)
    acc = fmaf(wgt[t], x[(size_t)b * n_in + cols[t]], acc);
  out[(size_t)b * n_out + j] = acc + bias[j];
}

extern "C" void kernel_launch(void* const* d_in, const int* in_sizes, int n_in_arrays,
                              void* d_out, int out_size, void* d_ws, size_t ws_size,
                              hipStream_t stream) {
  const float* x    = (const float*)d_in[0];
  const float* wgt  = (const float*)d_in[1];
  const float* bias = (const float*)d_in[2];
  const int*   rows = (const int*)d_in[3];
  const int*   cols = (const int*)d_in[4];
  float* out = (float*)d_out;

  const int nnz   = in_sizes[1];
  const int n_out = in_sizes[2];
  const int B     = out_size / n_out;           // 32
  const int n_in  = in_sizes[0] / B;            // 65536

  const int jblocks = (n_out + 31) / 32;
  const size_t xT_bytes = (size_t)n_in * 32 * sizeof(float);

  if (B == 32 && ws_size >= xT_bytes) {
    float* xT = (float*)d_ws;
    transpose_x_kernel<<<(n_in + 63) / 64, 256, 0, stream>>>(x, xT, n_in);
    ll_main_kernel<true><<<jblocks, 256, 0, stream>>>(
        xT, wgt, bias, rows, cols, out, n_in, n_out, nnz);
  } else if (B == 32) {
    ll_main_kernel<false><<<jblocks, 256, 0, stream>>>(
        x, wgt, bias, rows, cols, out, n_in, n_out, nnz);
  } else {
    int total = n_out * B;
    ll_naive_kernel<<<(total + 255) / 256, 256, 0, stream>>>(
        x, wgt, bias, rows, cols, out, n_in, n_out, nnz, B);
  }
}

// Round 4
// 62.843 us; speedup vs baseline: 2.5651x; 2.5651x over previous
//
#include <hip/hip_runtime.h>

// LocalLinear: out[b,j] = sum_{e: rows[e]==j} x[b, cols[e]] * w[e] + bias[j]
// B=32, N_IN=65536, N_OUT=65536, NNZ=2097152 (rows sorted, int32).
// R4: parallel row_ptr build (no serial binary search in main) + 8-lane-group
// float4 gather (4x MLP per vmem instruction), unroll-4 edge loop.

// ---------------- Kernel 1: transpose x (B x N_IN) -> xT (N_IN x 32) ----------------
__global__ __launch_bounds__(256) void transpose_x_kernel(
    const float* __restrict__ x, float* __restrict__ xT, int n_in) {
  __shared__ float t[32][65];
  int c0 = blockIdx.x * 64;
  for (int idx = threadIdx.x; idx < 32 * 64; idx += 256) {
    int b = idx >> 6, cl = idx & 63;
    int c = c0 + cl;
    t[b][cl] = (c < n_in) ? x[(size_t)b * n_in + c] : 0.0f;
  }
  __syncthreads();
  for (int idx = threadIdx.x; idx < 64 * 32; idx += 256) {
    int cl = idx >> 5, b = idx & 31;
    int c = c0 + cl;
    if (c < n_in) xT[(size_t)c * 32 + b] = t[b][cl];
  }
}

// ---------------- Kernel 2: row_ptr[j] = lower_bound(rows, j), fully parallel ----------------
__global__ __launch_bounds__(256) void build_rowptr_bs_kernel(
    const int* __restrict__ rows, int* __restrict__ row_ptr, int nnz, int n_out) {
  int j = blockIdx.x * blockDim.x + threadIdx.x;
  if (j > n_out) return;
  int lo = 0, hi = nnz;
  while (lo < hi) { int m = (lo + hi) >> 1; if (rows[m] < j) lo = m + 1; else hi = m; }
  row_ptr[j] = lo;
}

// ---------------- Kernel 3: main gather/accumulate ----------------
// 8-lane group g owns output j = jb+g; lane l gathers float4 (batches 4l..4l+3).
// Each vmem instruction carries 8 independent edges (one per group) x 128B columns.
__global__ __launch_bounds__(256) void ll_main4_kernel(
    const float4* __restrict__ xT4,      // n_in x 8 float4
    const float* __restrict__ wgt,
    const float* __restrict__ bias,
    const int* __restrict__ cols,
    const int* __restrict__ row_ptr,
    float* __restrict__ out,
    int n_out) {
  __shared__ float tile[32][33];
  int tid = threadIdx.x;
  int g = tid >> 3;        // group 0..31 == local j
  int l = tid & 7;         // lane in group: batches 4l..4l+3
  int jb = blockIdx.x * 32;
  int j = jb + g;
  float ax = 0.f, ay = 0.f, az = 0.f, aw = 0.f;
  if (j < n_out) {
    int s = row_ptr[j];
    int e = row_ptr[j + 1];
    for (int base = s; base < e; base += 4) {
      // guarded preload of up to 4 edges (independent scalar loads, L1-hot)
      int c0 = cols[base];
      float w0 = wgt[base];
      int c1 = c0, c2 = c0, c3 = c0;
      float w1 = 0.f, w2 = 0.f, w3 = 0.f;
      if (base + 1 < e) { c1 = cols[base + 1]; w1 = wgt[base + 1]; }
      if (base + 2 < e) { c2 = cols[base + 2]; w2 = wgt[base + 2]; }
      if (base + 3 < e) { c3 = cols[base + 3]; w3 = wgt[base + 3]; }
      // 4 independent 128B-coalesced gathers in flight
      float4 x0 = xT4[(size_t)c0 * 8 + l];
      float4 x1 = xT4[(size_t)c1 * 8 + l];
      float4 x2 = xT4[(size_t)c2 * 8 + l];
      float4 x3 = xT4[(size_t)c3 * 8 + l];
      ax = fmaf(w0, x0.x, ax); ay = fmaf(w0, x0.y, ay);
      az = fmaf(w0, x0.z, az); aw = fmaf(w0, x0.w, aw);
      ax = fmaf(w1, x1.x, ax); ay = fmaf(w1, x1.y, ay);
      az = fmaf(w1, x1.z, az); aw = fmaf(w1, x1.w, aw);
      ax = fmaf(w2, x2.x, ax); ay = fmaf(w2, x2.y, ay);
      az = fmaf(w2, x2.z, az); aw = fmaf(w2, x2.w, aw);
      ax = fmaf(w3, x3.x, ax); ay = fmaf(w3, x3.y, ay);
      az = fmaf(w3, x3.z, az); aw = fmaf(w3, x3.w, aw);
    }
  }
  tile[l * 4 + 0][g] = ax;
  tile[l * 4 + 1][g] = ay;
  tile[l * 4 + 2][g] = az;
  tile[l * 4 + 3][g] = aw;
  __syncthreads();
  // coalesced write of the 32x32 output tile (+bias)
  for (int idx = tid; idx < 32 * 32; idx += 256) {
    int bb = idx >> 5, jl = idx & 31;
    int jj = jb + jl;
    if (jj < n_out) out[(size_t)bb * n_out + jj] = tile[bb][jl] + bias[jj];
  }
}

// ---------------- Fallback: half-wave scheme w/ binary search (R3, known-good) ----------------
template <bool FAST>
__global__ __launch_bounds__(256) void ll_main_kernel(
    const float* __restrict__ xsrc,
    const float* __restrict__ wgt,
    const float* __restrict__ bias,
    const int* __restrict__ rows,
    const int* __restrict__ cols,
    float* __restrict__ out,
    int n_in, int n_out, int nnz) {
  __shared__ float tile[32][33];
  int tid = threadIdx.x;
  int b = tid & 31;
  int hw = tid >> 5;
  int jb = blockIdx.x * 32;
  for (int jq = 0; jq < 4; ++jq) {
    int jl = hw * 4 + jq;
    int j = jb + jl;
    float acc = 0.0f;
    if (j < n_out) {
      int lo = 0, hi = nnz;
      while (lo < hi) { int m = (lo + hi) >> 1; if (rows[m] < j) lo = m + 1; else hi = m; }
      int s = lo;
      hi = nnz;
      while (lo < hi) { int m = (lo + hi) >> 1; if (rows[m] <= j) lo = m + 1; else hi = m; }
      int e = lo;
      for (int t = s; t < e; ++t) {
        float xv = FAST ? xsrc[(size_t)cols[t] * 32 + b]
                        : xsrc[(size_t)b * n_in + cols[t]];
        acc = fmaf(wgt[t], xv, acc);
      }
    }
    tile[b][jl] = acc;
  }
  __syncthreads();
  for (int idx = tid; idx < 32 * 32; idx += 256) {
    int bb = idx >> 5, jl = idx & 31;
    int j = jb + jl;
    if (j < n_out) out[(size_t)bb * n_out + j] = tile[bb][jl] + bias[j];
  }
}

// ---------------- Last-resort naive (B != 32) ----------------
__global__ __launch_bounds__(256) void ll_naive_kernel(
    const float* __restrict__ x,
    const float* __restrict__ wgt,
    const float* __restrict__ bias,
    const int* __restrict__ rows,
    const int* __restrict__ cols,
    float* __restrict__ out,
    int n_in, int n_out, int nnz, int B) {
  int idx = blockIdx.x * blockDim.x + threadIdx.x;
  if (idx >= n_out * B) return;
  int j = idx % n_out;
  int b = idx / n_out;
  int lo = 0, hi = nnz;
  while (lo < hi) { int m = (lo + hi) >> 1; if (rows[m] < j) lo = m + 1; else hi = m; }
  int s = lo;
  hi = nnz;
  while (lo < hi) { int m = (lo + hi) >> 1; if (rows[m] <= j) lo = m + 1; else hi = m; }
  int e = lo;
  float acc = 0.0f;
  for (int t = s; t < e; ++t)
    acc = fmaf(wgt[t], x[(size_t)b * n_in + cols[t]], acc);
  out[(size_t)b * n_out + j] = acc + bias[j];
}

extern "C" void kernel_launch(void* const* d_in, const int* in_sizes, int n_in_arrays,
                              void* d_out, int out_size, void* d_ws, size_t ws_size,
                              hipStream_t stream) {
  const float* x    = (const float*)d_in[0];
  const float* wgt  = (const float*)d_in[1];
  const float* bias = (const float*)d_in[2];
  const int*   rows = (const int*)d_in[3];
  const int*   cols = (const int*)d_in[4];
  float* out = (float*)d_out;

  const int nnz   = in_sizes[1];
  const int n_out = in_sizes[2];
  const int B     = out_size / n_out;           // 32
  const int n_in  = in_sizes[0] / B;            // 65536

  const int jblocks = (n_out + 31) / 32;
  const size_t xT_bytes = (size_t)n_in * 32 * sizeof(float);
  const size_t rp_bytes = (size_t)(n_out + 1) * sizeof(int);

  if (B == 32 && ws_size >= xT_bytes + rp_bytes) {
    float* xT = (float*)d_ws;
    int* row_ptr = (int*)((char*)d_ws + xT_bytes);
    transpose_x_kernel<<<(n_in + 63) / 64, 256, 0, stream>>>(x, xT, n_in);
    build_rowptr_bs_kernel<<<(n_out + 256) / 256, 256, 0, stream>>>(rows, row_ptr, nnz, n_out);
    ll_main4_kernel<<<jblocks, 256, 0, stream>>>(
        (const float4*)xT, wgt, bias, cols, row_ptr, out, n_out);
  } else if (B == 32 && ws_size >= xT_bytes) {
    float* xT = (float*)d_ws;
    transpose_x_kernel<<<(n_in + 63) / 64, 256, 0, stream>>>(x, xT, n_in);
    ll_main_kernel<true><<<jblocks, 256, 0, stream>>>(
        xT, wgt, bias, rows, cols, out, n_in, n_out, nnz);
  } else if (B == 32) {
    ll_main_kernel<false><<<jblocks, 256, 0, stream>>>(
        x, wgt, bias, rows, cols, out, n_in, n_out, nnz);
  } else {
    int total = n_out * B;
    ll_naive_kernel<<<(total + 255) / 256, 256, 0, stream>>>(
        x, wgt, bias, rows, cols, out, n_in, n_out, nnz, B);
  }
}

// Round 6
// 47.679 us; speedup vs baseline: 3.3809x; 1.3181x over previous
//
#include <hip/hip_runtime.h>

// LocalLinear: out[b,j] = sum_{e: rows[e]==j} x[b, cols[e]] * w[e] + bias[j]
// B=32, N_IN=65536, N_OUT=65536, NNZ=2097152 (rows sorted, int32).
// R6 = R5 with macro-parameter collision fixed (EDGE(v,w): v.w -> v.w0).
// bf16 xT (4 MB -> per-XCD-L2-resident; half gather bytes), 4-lane groups
// (16 edge streams/wave), branch-free unroll-4, fused prep kernel.

typedef unsigned int u32;

static __device__ __forceinline__ u32 f2bf_bits(float f) {   // RNE f32->bf16
  u32 b = __builtin_bit_cast(u32, f);
  return (b + 0x7fffu + ((b >> 16) & 1u)) >> 16;
}
static __device__ __forceinline__ float bf_lo(u32 u) {
  return __builtin_bit_cast(float, u << 16);
}
static __device__ __forceinline__ float bf_hi(u32 u) {
  return __builtin_bit_cast(float, u & 0xffff0000u);
}

// ---------------- Prep: transpose x -> bf16 xT  +  row_ptr build (fused) ----------------
__global__ __launch_bounds__(256) void prep_kernel(
    const float* __restrict__ x, u32* __restrict__ xTb,   // xTb: n_in x 16 u32 (32 bf16)
    const int* __restrict__ rows, int* __restrict__ row_ptr,
    int n_in, int n_out, int nnz, int tblocks) {
  if ((int)blockIdx.x < tblocks) {
    __shared__ float t[32][65];
    int c0 = blockIdx.x * 64;
    for (int idx = threadIdx.x; idx < 32 * 64; idx += 256) {
      int b = idx >> 6, cl = idx & 63;
      int c = c0 + cl;
      t[b][cl] = (c < n_in) ? x[(size_t)b * n_in + c] : 0.f;
    }
    __syncthreads();
    for (int idx = threadIdx.x; idx < 64 * 16; idx += 256) {
      int cl = idx >> 4, bp = idx & 15;   // bp = batch pair
      int c = c0 + cl;
      if (c < n_in) {
        u32 v = f2bf_bits(t[2 * bp][cl]) | (f2bf_bits(t[2 * bp + 1][cl]) << 16);
        xTb[(size_t)c * 16 + bp] = v;
      }
    }
  } else {
    int j = ((int)blockIdx.x - tblocks) * 256 + threadIdx.x;
    if (j <= n_out) {
      int lo = 0, hi = nnz;
      while (lo < hi) { int m = (lo + hi) >> 1; if (rows[m] < j) lo = m + 1; else hi = m; }
      row_ptr[j] = lo;
    }
  }
}

// ---------------- Main: 4-lane group per j, bf16 gather, branch-free unroll-4 ----------------
__global__ __launch_bounds__(256) void ll_main_bf16_kernel(
    const uint4* __restrict__ xTb4,     // n_in x 4 uint4 (column = 64 B)
    const float* __restrict__ wgt,
    const float* __restrict__ bias,
    const int* __restrict__ cols,
    const int* __restrict__ row_ptr,
    float* __restrict__ out, int n_out) {
  __shared__ float tile[32][65];
  int tid = threadIdx.x;
  int g = tid >> 2;        // group 0..63 == local j
  int l = tid & 3;         // lane in group: batches 8l..8l+7
  int jb = blockIdx.x * 64;
  int j = jb + g;
  float a0 = 0, a1 = 0, a2 = 0, a3 = 0, a4 = 0, a5 = 0, a6 = 0, a7 = 0;
  if (j < n_out) {
    int s = row_ptr[j], e = row_ptr[j + 1];
    for (int base = s; base < e; base += 4) {
      int last = e - 1;
      int i1 = min(base + 1, last);
      int i2 = min(base + 2, last);
      int i3 = min(base + 3, last);
      int c0 = cols[base], c1 = cols[i1], c2 = cols[i2], c3 = cols[i3];
      float w0 = wgt[base];
      float w1 = (base + 1 <= last) ? wgt[i1] : 0.f;
      float w2 = (base + 2 <= last) ? wgt[i2] : 0.f;
      float w3 = (base + 3 <= last) ? wgt[i3] : 0.f;
      uint4 v0 = xTb4[(size_t)c0 * 4 + l];
      uint4 v1 = xTb4[(size_t)c1 * 4 + l];
      uint4 v2 = xTb4[(size_t)c2 * 4 + l];
      uint4 v3 = xTb4[(size_t)c3 * 4 + l];
#define EDGE(V, W) \
      a0 = fmaf(W, bf_lo(V.x), a0); a1 = fmaf(W, bf_hi(V.x), a1); \
      a2 = fmaf(W, bf_lo(V.y), a2); a3 = fmaf(W, bf_hi(V.y), a3); \
      a4 = fmaf(W, bf_lo(V.z), a4); a5 = fmaf(W, bf_hi(V.z), a5); \
      a6 = fmaf(W, bf_lo(V.w), a6); a7 = fmaf(W, bf_hi(V.w), a7);
      EDGE(v0, w0) EDGE(v1, w1) EDGE(v2, w2) EDGE(v3, w3)
#undef EDGE
    }
  }
  int b0 = l * 8;
  tile[b0 + 0][g] = a0; tile[b0 + 1][g] = a1; tile[b0 + 2][g] = a2; tile[b0 + 3][g] = a3;
  tile[b0 + 4][g] = a4; tile[b0 + 5][g] = a5; tile[b0 + 6][g] = a6; tile[b0 + 7][g] = a7;
  __syncthreads();
  for (int idx = tid; idx < 32 * 64; idx += 256) {
    int bb = idx >> 6, jl = idx & 63;
    int jj = jb + jl;
    if (jj < n_out) out[(size_t)bb * n_out + jj] = tile[bb][jl] + bias[jj];
  }
}

// ---------------- Fallbacks (R3/R4, known-good fp32 paths) ----------------
__global__ __launch_bounds__(256) void transpose_x_kernel(
    const float* __restrict__ x, float* __restrict__ xT, int n_in) {
  __shared__ float t[32][65];
  int c0 = blockIdx.x * 64;
  for (int idx = threadIdx.x; idx < 32 * 64; idx += 256) {
    int b = idx >> 6, cl = idx & 63;
    int c = c0 + cl;
    t[b][cl] = (c < n_in) ? x[(size_t)b * n_in + c] : 0.0f;
  }
  __syncthreads();
  for (int idx = threadIdx.x; idx < 64 * 32; idx += 256) {
    int cl = idx >> 5, b = idx & 31;
    int c = c0 + cl;
    if (c < n_in) xT[(size_t)c * 32 + b] = t[b][cl];
  }
}

__global__ __launch_bounds__(256) void build_rowptr_bs_kernel(
    const int* __restrict__ rows, int* __restrict__ row_ptr, int nnz, int n_out) {
  int j = blockIdx.x * blockDim.x + threadIdx.x;
  if (j > n_out) return;
  int lo = 0, hi = nnz;
  while (lo < hi) { int m = (lo + hi) >> 1; if (rows[m] < j) lo = m + 1; else hi = m; }
  row_ptr[j] = lo;
}

__global__ __launch_bounds__(256) void ll_main4_kernel(
    const float4* __restrict__ xT4,
    const float* __restrict__ wgt,
    const float* __restrict__ bias,
    const int* __restrict__ cols,
    const int* __restrict__ row_ptr,
    float* __restrict__ out, int n_out) {
  __shared__ float tile[32][33];
  int tid = threadIdx.x;
  int g = tid >> 3;
  int l = tid & 7;
  int jb = blockIdx.x * 32;
  int j = jb + g;
  float ax = 0.f, ay = 0.f, az = 0.f, aw = 0.f;
  if (j < n_out) {
    int s = row_ptr[j];
    int e = row_ptr[j + 1];
    for (int base = s; base < e; base += 4) {
      int last = e - 1;
      int i1 = min(base + 1, last), i2 = min(base + 2, last), i3 = min(base + 3, last);
      int c0 = cols[base], c1 = cols[i1], c2 = cols[i2], c3 = cols[i3];
      float w0 = wgt[base];
      float w1 = (base + 1 <= last) ? wgt[i1] : 0.f;
      float w2 = (base + 2 <= last) ? wgt[i2] : 0.f;
      float w3 = (base + 3 <= last) ? wgt[i3] : 0.f;
      float4 x0 = xT4[(size_t)c0 * 8 + l];
      float4 x1 = xT4[(size_t)c1 * 8 + l];
      float4 x2 = xT4[(size_t)c2 * 8 + l];
      float4 x3 = xT4[(size_t)c3 * 8 + l];
      ax = fmaf(w0, x0.x, ax); ay = fmaf(w0, x0.y, ay);
      az = fmaf(w0, x0.z, az); aw = fmaf(w0, x0.w, aw);
      ax = fmaf(w1, x1.x, ax); ay = fmaf(w1, x1.y, ay);
      az = fmaf(w1, x1.z, az); aw = fmaf(w1, x1.w, aw);
      ax = fmaf(w2, x2.x, ax); ay = fmaf(w2, x2.y, ay);
      az = fmaf(w2, x2.z, az); aw = fmaf(w2, x2.w, aw);
      ax = fmaf(w3, x3.x, ax); ay = fmaf(w3, x3.y, ay);
      az = fmaf(w3, x3.z, az); aw = fmaf(w3, x3.w, aw);
    }
  }
  tile[l * 4 + 0][g] = ax;
  tile[l * 4 + 1][g] = ay;
  tile[l * 4 + 2][g] = az;
  tile[l * 4 + 3][g] = aw;
  __syncthreads();
  for (int idx = tid; idx < 32 * 32; idx += 256) {
    int bb = idx >> 5, jl = idx & 31;
    int jj = jb + jl;
    if (jj < n_out) out[(size_t)bb * n_out + jj] = tile[bb][jl] + bias[jj];
  }
}

__global__ __launch_bounds__(256) void ll_naive_kernel(
    const float* __restrict__ x,
    const float* __restrict__ wgt,
    const float* __restrict__ bias,
    const int* __restrict__ rows,
    const int* __restrict__ cols,
    float* __restrict__ out,
    int n_in, int n_out, int nnz, int B) {
  int idx = blockIdx.x * blockDim.x + threadIdx.x;
  if (idx >= n_out * B) return;
  int j = idx % n_out;
  int b = idx / n_out;
  int lo = 0, hi = nnz;
  while (lo < hi) { int m = (lo + hi) >> 1; if (rows[m] < j) lo = m + 1; else hi = m; }
  int s = lo;
  hi = nnz;
  while (lo < hi) { int m = (lo + hi) >> 1; if (rows[m] <= j) lo = m + 1; else hi = m; }
  int e = lo;
  float acc = 0.0f;
  for (int t = s; t < e; ++t)
    acc = fmaf(wgt[t], x[(size_t)b * n_in + cols[t]], acc);
  out[(size_t)b * n_out + j] = acc + bias[j];
}

extern "C" void kernel_launch(void* const* d_in, const int* in_sizes, int n_in_arrays,
                              void* d_out, int out_size, void* d_ws, size_t ws_size,
                              hipStream_t stream) {
  const float* x    = (const float*)d_in[0];
  const float* wgt  = (const float*)d_in[1];
  const float* bias = (const float*)d_in[2];
  const int*   rows = (const int*)d_in[3];
  const int*   cols = (const int*)d_in[4];
  float* out = (float*)d_out;

  const int nnz   = in_sizes[1];
  const int n_out = in_sizes[2];
  const int B     = out_size / n_out;           // 32
  const int n_in  = in_sizes[0] / B;            // 65536

  const size_t xTb_bytes = (size_t)n_in * 32 * 2;              // bf16 table
  const size_t xT_bytes  = (size_t)n_in * 32 * sizeof(float);  // fp32 table
  const size_t rp_bytes  = (size_t)(n_out + 1) * sizeof(int);

  if (B == 32 && ws_size >= xTb_bytes + rp_bytes) {
    u32* xTb = (u32*)d_ws;
    int* row_ptr = (int*)((char*)d_ws + xTb_bytes);
    int tblocks = (n_in + 63) / 64;
    int rblocks = (n_out + 1 + 255) / 256;
    prep_kernel<<<tblocks + rblocks, 256, 0, stream>>>(
        x, xTb, rows, row_ptr, n_in, n_out, nnz, tblocks);
    ll_main_bf16_kernel<<<(n_out + 63) / 64, 256, 0, stream>>>(
        (const uint4*)xTb, wgt, bias, cols, row_ptr, out, n_out);
  } else if (B == 32 && ws_size >= xT_bytes + rp_bytes) {
    float* xT = (float*)d_ws;
    int* row_ptr = (int*)((char*)d_ws + xT_bytes);
    transpose_x_kernel<<<(n_in + 63) / 64, 256, 0, stream>>>(x, xT, n_in);
    build_rowptr_bs_kernel<<<(n_out + 256) / 256, 256, 0, stream>>>(rows, row_ptr, nnz, n_out);
    ll_main4_kernel<<<(n_out + 31) / 32, 256, 0, stream>>>(
        (const float4*)xT, wgt, bias, cols, row_ptr, out, n_out);
  } else {
    int total = n_out * B;
    ll_naive_kernel<<<(total + 255) / 256, 256, 0, stream>>>(
        x, wgt, bias, rows, cols, out, n_in, n_out, nnz, B);
  }
}

// Round 7
// 43.992 us; speedup vs baseline: 3.6642x; 1.0838x over previous
//
#include <hip/hip_runtime.h>

// LocalLinear: out[b,j] = sum_{e: rows[e]==j} x[b, cols[e]] * w[e] + bias[j]
// B=32, N_IN=65536, N_OUT=65536, NNZ=2097152 (rows sorted, int32).
// R7: unroll-8 edge loop (8 in-flight gathers/group), float4 writeout,
// float4 transpose read. bf16 xT table (4 MB), 4-lane groups.

typedef unsigned int u32;

static __device__ __forceinline__ u32 f2bf_bits(float f) {   // RNE f32->bf16
  u32 b = __builtin_bit_cast(u32, f);
  return (b + 0x7fffu + ((b >> 16) & 1u)) >> 16;
}
static __device__ __forceinline__ float bf_lo(u32 u) {
  return __builtin_bit_cast(float, u << 16);
}
static __device__ __forceinline__ float bf_hi(u32 u) {
  return __builtin_bit_cast(float, u & 0xffff0000u);
}

// ---------------- Prep: transpose x -> bf16 xT  +  row_ptr build (fused) ----------------
__global__ __launch_bounds__(256) void prep_kernel(
    const float* __restrict__ x, u32* __restrict__ xTb,   // xTb: n_in x 16 u32 (32 bf16)
    const int* __restrict__ rows, int* __restrict__ row_ptr,
    int n_in, int n_out, int nnz, int tblocks) {
  if ((int)blockIdx.x < tblocks) {
    __shared__ float t[32][65];
    int c0 = blockIdx.x * 64;
    if (c0 + 64 <= n_in) {
      // fast path: float4 reads (x is 16B-aligned, rows are n_in-strided)
      const float4* x4 = (const float4*)x;
      for (int idx = threadIdx.x; idx < 32 * 16; idx += 256) {
        int b = idx >> 4, q = idx & 15;
        float4 v = x4[((size_t)b * n_in + c0) / 4 + q];
        t[b][q * 4 + 0] = v.x; t[b][q * 4 + 1] = v.y;
        t[b][q * 4 + 2] = v.z; t[b][q * 4 + 3] = v.w;
      }
    } else {
      for (int idx = threadIdx.x; idx < 32 * 64; idx += 256) {
        int b = idx >> 6, cl = idx & 63;
        int c = c0 + cl;
        t[b][cl] = (c < n_in) ? x[(size_t)b * n_in + c] : 0.f;
      }
    }
    __syncthreads();
    for (int idx = threadIdx.x; idx < 64 * 16; idx += 256) {
      int cl = idx >> 4, bp = idx & 15;   // bp = batch pair
      int c = c0 + cl;
      if (c < n_in) {
        u32 v = f2bf_bits(t[2 * bp][cl]) | (f2bf_bits(t[2 * bp + 1][cl]) << 16);
        xTb[(size_t)c * 16 + bp] = v;
      }
    }
  } else {
    int j = ((int)blockIdx.x - tblocks) * 256 + threadIdx.x;
    if (j <= n_out) {
      int lo = 0, hi = nnz;
      while (lo < hi) { int m = (lo + hi) >> 1; if (rows[m] < j) lo = m + 1; else hi = m; }
      row_ptr[j] = lo;
    }
  }
}

// ---------------- Main: 4-lane group per j, bf16 gather, branch-free unroll-8 ----------------
__global__ __launch_bounds__(256) void ll_main_bf16_kernel(
    const uint4* __restrict__ xTb4,     // n_in x 4 uint4 (column = 64 B)
    const float* __restrict__ wgt,
    const float4* __restrict__ bias4,
    const int* __restrict__ cols,
    const int* __restrict__ row_ptr,
    float4* __restrict__ out4, int n_out) {
  __shared__ float tile[32][65];
  int tid = threadIdx.x;
  int g = tid >> 2;        // group 0..63 == local j
  int l = tid & 3;         // lane in group: batches 8l..8l+7
  int jb = blockIdx.x * 64;
  int j = jb + g;
  float a0 = 0, a1 = 0, a2 = 0, a3 = 0, a4 = 0, a5 = 0, a6 = 0, a7 = 0;
  if (j < n_out) {
    int s = row_ptr[j], e = row_ptr[j + 1];
    int last = e - 1;
    for (int base = s; base < e; base += 8) {
      int i1 = min(base + 1, last), i2 = min(base + 2, last), i3 = min(base + 3, last);
      int i4 = min(base + 4, last), i5 = min(base + 5, last), i6 = min(base + 6, last);
      int i7 = min(base + 7, last);
      int c0 = cols[base], c1 = cols[i1], c2 = cols[i2], c3 = cols[i3];
      int c4 = cols[i4], c5 = cols[i5], c6 = cols[i6], c7 = cols[i7];
      float w0 = wgt[base];
      float w1 = (base + 1 <= last) ? wgt[i1] : 0.f;
      float w2 = (base + 2 <= last) ? wgt[i2] : 0.f;
      float w3 = (base + 3 <= last) ? wgt[i3] : 0.f;
      float w4 = (base + 4 <= last) ? wgt[i4] : 0.f;
      float w5 = (base + 5 <= last) ? wgt[i5] : 0.f;
      float w6 = (base + 6 <= last) ? wgt[i6] : 0.f;
      float w7 = (base + 7 <= last) ? wgt[i7] : 0.f;
      uint4 v0 = xTb4[(size_t)c0 * 4 + l];
      uint4 v1 = xTb4[(size_t)c1 * 4 + l];
      uint4 v2 = xTb4[(size_t)c2 * 4 + l];
      uint4 v3 = xTb4[(size_t)c3 * 4 + l];
      uint4 v4 = xTb4[(size_t)c4 * 4 + l];
      uint4 v5 = xTb4[(size_t)c5 * 4 + l];
      uint4 v6 = xTb4[(size_t)c6 * 4 + l];
      uint4 v7 = xTb4[(size_t)c7 * 4 + l];
#define EDGE(V, W) \
      a0 = fmaf(W, bf_lo(V.x), a0); a1 = fmaf(W, bf_hi(V.x), a1); \
      a2 = fmaf(W, bf_lo(V.y), a2); a3 = fmaf(W, bf_hi(V.y), a3); \
      a4 = fmaf(W, bf_lo(V.z), a4); a5 = fmaf(W, bf_hi(V.z), a5); \
      a6 = fmaf(W, bf_lo(V.w), a6); a7 = fmaf(W, bf_hi(V.w), a7);
      EDGE(v0, w0) EDGE(v1, w1) EDGE(v2, w2) EDGE(v3, w3)
      EDGE(v4, w4) EDGE(v5, w5) EDGE(v6, w6) EDGE(v7, w7)
#undef EDGE
    }
  }
  int b0 = l * 8;
  tile[b0 + 0][g] = a0; tile[b0 + 1][g] = a1; tile[b0 + 2][g] = a2; tile[b0 + 3][g] = a3;
  tile[b0 + 4][g] = a4; tile[b0 + 5][g] = a5; tile[b0 + 6][g] = a6; tile[b0 + 7][g] = a7;
  __syncthreads();
  // vectorized writeout: 32 rows x 16 float4 (+bias)
  for (int slot = tid; slot < 32 * 16; slot += 256) {
    int bb = slot >> 4, q = slot & 15;
    int jj = jb + q * 4;
    if (jj + 3 < n_out) {
      float4 bv = bias4[jj / 4];
      float4 o;
      o.x = tile[bb][q * 4 + 0] + bv.x;
      o.y = tile[bb][q * 4 + 1] + bv.y;
      o.z = tile[bb][q * 4 + 2] + bv.z;
      o.w = tile[bb][q * 4 + 3] + bv.w;
      out4[((size_t)bb * n_out + jj) / 4] = o;
    } else {
      float* out = (float*)out4;
      const float* bias = (const float*)bias4;
      for (int d = 0; d < 4; ++d)
        if (jj + d < n_out)
          out[(size_t)bb * n_out + jj + d] = tile[bb][q * 4 + d] + bias[jj + d];
    }
  }
}

// ---------------- Fallback: fp32 path (R4, known-good) ----------------
__global__ __launch_bounds__(256) void transpose_x_kernel(
    const float* __restrict__ x, float* __restrict__ xT, int n_in) {
  __shared__ float t[32][65];
  int c0 = blockIdx.x * 64;
  for (int idx = threadIdx.x; idx < 32 * 64; idx += 256) {
    int b = idx >> 6, cl = idx & 63;
    int c = c0 + cl;
    t[b][cl] = (c < n_in) ? x[(size_t)b * n_in + c] : 0.0f;
  }
  __syncthreads();
  for (int idx = threadIdx.x; idx < 64 * 32; idx += 256) {
    int cl = idx >> 5, b = idx & 31;
    int c = c0 + cl;
    if (c < n_in) xT[(size_t)c * 32 + b] = t[b][cl];
  }
}

__global__ __launch_bounds__(256) void build_rowptr_bs_kernel(
    const int* __restrict__ rows, int* __restrict__ row_ptr, int nnz, int n_out) {
  int j = blockIdx.x * blockDim.x + threadIdx.x;
  if (j > n_out) return;
  int lo = 0, hi = nnz;
  while (lo < hi) { int m = (lo + hi) >> 1; if (rows[m] < j) lo = m + 1; else hi = m; }
  row_ptr[j] = lo;
}

__global__ __launch_bounds__(256) void ll_main4_kernel(
    const float4* __restrict__ xT4,
    const float* __restrict__ wgt,
    const float* __restrict__ bias,
    const int* __restrict__ cols,
    const int* __restrict__ row_ptr,
    float* __restrict__ out, int n_out) {
  __shared__ float tile[32][33];
  int tid = threadIdx.x;
  int g = tid >> 3;
  int l = tid & 7;
  int jb = blockIdx.x * 32;
  int j = jb + g;
  float ax = 0.f, ay = 0.f, az = 0.f, aw = 0.f;
  if (j < n_out) {
    int s = row_ptr[j];
    int e = row_ptr[j + 1];
    for (int base = s; base < e; base += 4) {
      int last = e - 1;
      int i1 = min(base + 1, last), i2 = min(base + 2, last), i3 = min(base + 3, last);
      int c0 = cols[base], c1 = cols[i1], c2 = cols[i2], c3 = cols[i3];
      float w0 = wgt[base];
      float w1 = (base + 1 <= last) ? wgt[i1] : 0.f;
      float w2 = (base + 2 <= last) ? wgt[i2] : 0.f;
      float w3 = (base + 3 <= last) ? wgt[i3] : 0.f;
      float4 x0 = xT4[(size_t)c0 * 8 + l];
      float4 x1 = xT4[(size_t)c1 * 8 + l];
      float4 x2 = xT4[(size_t)c2 * 8 + l];
      float4 x3 = xT4[(size_t)c3 * 8 + l];
      ax = fmaf(w0, x0.x, ax); ay = fmaf(w0, x0.y, ay);
      az = fmaf(w0, x0.z, az); aw = fmaf(w0, x0.w, aw);
      ax = fmaf(w1, x1.x, ax); ay = fmaf(w1, x1.y, ay);
      az = fmaf(w1, x1.z, az); aw = fmaf(w1, x1.w, aw);
      ax = fmaf(w2, x2.x, ax); ay = fmaf(w2, x2.y, ay);
      az = fmaf(w2, x2.z, az); aw = fmaf(w2, x2.w, aw);
      ax = fmaf(w3, x3.x, ax); ay = fmaf(w3, x3.y, ay);
      az = fmaf(w3, x3.z, az); aw = fmaf(w3, x3.w, aw);
    }
  }
  tile[l * 4 + 0][g] = ax;
  tile[l * 4 + 1][g] = ay;
  tile[l * 4 + 2][g] = az;
  tile[l * 4 + 3][g] = aw;
  __syncthreads();
  for (int idx = tid; idx < 32 * 32; idx += 256) {
    int bb = idx >> 5, jl = idx & 31;
    int jj = jb + jl;
    if (jj < n_out) out[(size_t)bb * n_out + jj] = tile[bb][jl] + bias[jj];
  }
}

__global__ __launch_bounds__(256) void ll_naive_kernel(
    const float* __restrict__ x,
    const float* __restrict__ wgt,
    const float* __restrict__ bias,
    const int* __restrict__ rows,
    const int* __restrict__ cols,
    float* __restrict__ out,
    int n_in, int n_out, int nnz, int B) {
  int idx = blockIdx.x * blockDim.x + threadIdx.x;
  if (idx >= n_out * B) return;
  int j = idx % n_out;
  int b = idx / n_out;
  int lo = 0, hi = nnz;
  while (lo < hi) { int m = (lo + hi) >> 1; if (rows[m] < j) lo = m + 1; else hi = m; }
  int s = lo;
  hi = nnz;
  while (lo < hi) { int m = (lo + hi) >> 1; if (rows[m] <= j) lo = m + 1; else hi = m; }
  int e = lo;
  float acc = 0.0f;
  for (int t = s; t < e; ++t)
    acc = fmaf(wgt[t], x[(size_t)b * n_in + cols[t]], acc);
  out[(size_t)b * n_out + j] = acc + bias[j];
}

extern "C" void kernel_launch(void* const* d_in, const int* in_sizes, int n_in_arrays,
                              void* d_out, int out_size, void* d_ws, size_t ws_size,
                              hipStream_t stream) {
  const float* x    = (const float*)d_in[0];
  const float* wgt  = (const float*)d_in[1];
  const float* bias = (const float*)d_in[2];
  const int*   rows = (const int*)d_in[3];
  const int*   cols = (const int*)d_in[4];
  float* out = (float*)d_out;

  const int nnz   = in_sizes[1];
  const int n_out = in_sizes[2];
  const int B     = out_size / n_out;           // 32
  const int n_in  = in_sizes[0] / B;            // 65536

  const size_t xTb_bytes = (size_t)n_in * 32 * 2;              // bf16 table
  const size_t xT_bytes  = (size_t)n_in * 32 * sizeof(float);  // fp32 table
  const size_t rp_bytes  = (size_t)(n_out + 1) * sizeof(int);

  if (B == 32 && ws_size >= xTb_bytes + rp_bytes) {
    u32* xTb = (u32*)d_ws;
    int* row_ptr = (int*)((char*)d_ws + xTb_bytes);
    int tblocks = (n_in + 63) / 64;
    int rblocks = (n_out + 1 + 255) / 256;
    prep_kernel<<<tblocks + rblocks, 256, 0, stream>>>(
        x, xTb, rows, row_ptr, n_in, n_out, nnz, tblocks);
    ll_main_bf16_kernel<<<(n_out + 63) / 64, 256, 0, stream>>>(
        (const uint4*)xTb, wgt, (const float4*)bias, cols, row_ptr,
        (float4*)out, n_out);
  } else if (B == 32 && ws_size >= xT_bytes + rp_bytes) {
    float* xT = (float*)d_ws;
    int* row_ptr = (int*)((char*)d_ws + xT_bytes);
    transpose_x_kernel<<<(n_in + 63) / 64, 256, 0, stream>>>(x, xT, n_in);
    build_rowptr_bs_kernel<<<(n_out + 256) / 256, 256, 0, stream>>>(rows, row_ptr, nnz, n_out);
    ll_main4_kernel<<<(n_out + 31) / 32, 256, 0, stream>>>(
        (const float4*)xT, wgt, bias, cols, row_ptr, out, n_out);
  } else {
    int total = n_out * B;
    ll_naive_kernel<<<(total + 255) / 256, 256, 0, stream>>>(
        x, wgt, bias, rows, cols, out, n_in, n_out, nnz, B);
  }
}

// Round 8
// 37.832 us; speedup vs baseline: 4.2609x; 1.1628x over previous
//
#include <hip/hip_runtime.h>

// LocalLinear: out[b,j] = sum_{e: rows[e]==j} x[b, cols[e]] * w[e] + bias[j]
// B=32, N_IN=65536, N_OUT=65536, NNZ=2097152 (rows sorted, int32).
// R8: 512-thread blocks (32 waves/CU), lane-distributed cols/wgt loads +
// shfl broadcast, scatter-built row_ptr, bf16 xT table (4 MB).

typedef unsigned int u32;

static __device__ __forceinline__ u32 f2bf_bits(float f) {   // RNE f32->bf16
  u32 b = __builtin_bit_cast(u32, f);
  return (b + 0x7fffu + ((b >> 16) & 1u)) >> 16;
}
static __device__ __forceinline__ float bf_lo(u32 u) {
  return __builtin_bit_cast(float, u << 16);
}
static __device__ __forceinline__ float bf_hi(u32 u) {
  return __builtin_bit_cast(float, u & 0xffff0000u);
}

// ---------------- Prep: transpose x -> bf16 xT  +  scatter row_ptr (fused) ----------------
__global__ __launch_bounds__(256) void prep_kernel(
    const float* __restrict__ x, u32* __restrict__ xTb,   // xTb: n_in x 16 u32 (32 bf16)
    const int* __restrict__ rows, int* __restrict__ row_ptr,
    int n_in, int n_out, int nnz, int tblocks) {
  if ((int)blockIdx.x < tblocks) {
    __shared__ float t[32][65];
    int c0 = blockIdx.x * 64;
    if (c0 + 64 <= n_in) {
      const float4* x4 = (const float4*)x;
      for (int idx = threadIdx.x; idx < 32 * 16; idx += 256) {
        int b = idx >> 4, q = idx & 15;
        float4 v = x4[((size_t)b * n_in + c0) / 4 + q];
        t[b][q * 4 + 0] = v.x; t[b][q * 4 + 1] = v.y;
        t[b][q * 4 + 2] = v.z; t[b][q * 4 + 3] = v.w;
      }
    } else {
      for (int idx = threadIdx.x; idx < 32 * 64; idx += 256) {
        int b = idx >> 6, cl = idx & 63;
        int c = c0 + cl;
        t[b][cl] = (c < n_in) ? x[(size_t)b * n_in + c] : 0.f;
      }
    }
    __syncthreads();
    for (int idx = threadIdx.x; idx < 64 * 16; idx += 256) {
      int cl = idx >> 4, bp = idx & 15;   // bp = batch pair
      int c = c0 + cl;
      if (c < n_in) {
        u32 v = f2bf_bits(t[2 * bp][cl]) | (f2bf_bits(t[2 * bp + 1][cl]) << 16);
        xTb[(size_t)c * 16 + bp] = v;
      }
    }
  } else {
    // scatter CSR build: row_ptr[j] = first e with rows[e] >= j
    int e = ((int)blockIdx.x - tblocks) * 256 + threadIdx.x;
    if (e < nnz) {
      int r = rows[e];
      int rp = (e == 0) ? -1 : rows[e - 1];
      for (int j = rp + 1; j <= r; ++j) row_ptr[j] = e;
      if (e == nnz - 1)
        for (int j = r + 1; j <= n_out; ++j) row_ptr[j] = nnz;
    }
  }
}

// ---------------- Main: 4-lane groups, half-split edge ranges, shfl broadcast ----------------
// 512 threads = 8 waves. Waves 0-3: half 0, waves 4-7: half 1 of the same 64 j's.
// Half h processes edge chunks [s+4h + 8k, +4) — disjoint, covers [s,e).
__global__ __launch_bounds__(512, 8) void ll_main_bf16_kernel(
    const uint4* __restrict__ xTb4,     // n_in x 4 uint4 (column = 64 B)
    const float* __restrict__ wgt,
    const float4* __restrict__ bias4,
    const int* __restrict__ cols,
    const int* __restrict__ row_ptr,
    float4* __restrict__ out4, int n_out) {
  __shared__ float tile[32][65];
  int tid = threadIdx.x;
  int lane = tid & 63;
  int l = lane & 3;              // lane in group: batches 8l..8l+7
  int gw = lane >> 2;            // group within wave 0..15
  int wv = tid >> 6;             // wave 0..7
  int half = wv >> 2;            // 0 or 1
  int g = (wv & 3) * 16 + gw;    // group 0..63 == local j
  int gb = lane & 60;            // group base lane (for shfl)
  int jb = blockIdx.x * 64;
  int j = jb + g;
  float a0 = 0, a1 = 0, a2 = 0, a3 = 0, a4 = 0, a5 = 0, a6 = 0, a7 = 0;
  if (j < n_out) {
    int s = row_ptr[j], e = row_ptr[j + 1];
    int last = e - 1;
    for (int base = s + half * 4; base < e; base += 8) {
      int il = min(base + l, last);
      int cl_ = cols[il];                                  // 4 edges per instr
      float wl_ = (base + l <= last) ? wgt[il] : 0.f;
#define EDGE_K(K) { \
      int   ck = __shfl(cl_, gb | K); \
      float wk = __shfl(wl_, gb | K); \
      uint4 v  = xTb4[(size_t)ck * 4 + l]; \
      a0 = fmaf(wk, bf_lo(v.x), a0); a1 = fmaf(wk, bf_hi(v.x), a1); \
      a2 = fmaf(wk, bf_lo(v.y), a2); a3 = fmaf(wk, bf_hi(v.y), a3); \
      a4 = fmaf(wk, bf_lo(v.z), a4); a5 = fmaf(wk, bf_hi(v.z), a5); \
      a6 = fmaf(wk, bf_lo(v.w), a6); a7 = fmaf(wk, bf_hi(v.w), a7); }
      EDGE_K(0) EDGE_K(1) EDGE_K(2) EDGE_K(3)
#undef EDGE_K
    }
  }
  int b0 = l * 8;
  if (half == 0) {
    tile[b0 + 0][g] = a0; tile[b0 + 1][g] = a1; tile[b0 + 2][g] = a2; tile[b0 + 3][g] = a3;
    tile[b0 + 4][g] = a4; tile[b0 + 5][g] = a5; tile[b0 + 6][g] = a6; tile[b0 + 7][g] = a7;
  }
  __syncthreads();
  if (half == 1) {
    tile[b0 + 0][g] += a0; tile[b0 + 1][g] += a1; tile[b0 + 2][g] += a2; tile[b0 + 3][g] += a3;
    tile[b0 + 4][g] += a4; tile[b0 + 5][g] += a5; tile[b0 + 6][g] += a6; tile[b0 + 7][g] += a7;
  }
  __syncthreads();
  // vectorized writeout: 512 threads, one float4 each (32 rows x 16 quads)
  {
    int bb = tid >> 4, q = tid & 15;
    int jj = jb + q * 4;
    if (jj + 3 < n_out) {
      float4 bv = bias4[jj / 4];
      float4 o;
      o.x = tile[bb][q * 4 + 0] + bv.x;
      o.y = tile[bb][q * 4 + 1] + bv.y;
      o.z = tile[bb][q * 4 + 2] + bv.z;
      o.w = tile[bb][q * 4 + 3] + bv.w;
      out4[((size_t)bb * n_out + jj) / 4] = o;
    } else {
      float* out = (float*)out4;
      const float* bias = (const float*)bias4;
      for (int d = 0; d < 4; ++d)
        if (jj + d < n_out)
          out[(size_t)bb * n_out + jj + d] = tile[bb][q * 4 + d] + bias[jj + d];
    }
  }
}

// ---------------- Fallback: fp32 path (R4, known-good) ----------------
__global__ __launch_bounds__(256) void transpose_x_kernel(
    const float* __restrict__ x, float* __restrict__ xT, int n_in) {
  __shared__ float t[32][65];
  int c0 = blockIdx.x * 64;
  for (int idx = threadIdx.x; idx < 32 * 64; idx += 256) {
    int b = idx >> 6, cl = idx & 63;
    int c = c0 + cl;
    t[b][cl] = (c < n_in) ? x[(size_t)b * n_in + c] : 0.0f;
  }
  __syncthreads();
  for (int idx = threadIdx.x; idx < 64 * 32; idx += 256) {
    int cl = idx >> 5, b = idx & 31;
    int c = c0 + cl;
    if (c < n_in) xT[(size_t)c * 32 + b] = t[b][cl];
  }
}

__global__ __launch_bounds__(256) void build_rowptr_bs_kernel(
    const int* __restrict__ rows, int* __restrict__ row_ptr, int nnz, int n_out) {
  int j = blockIdx.x * blockDim.x + threadIdx.x;
  if (j > n_out) return;
  int lo = 0, hi = nnz;
  while (lo < hi) { int m = (lo + hi) >> 1; if (rows[m] < j) lo = m + 1; else hi = m; }
  row_ptr[j] = lo;
}

__global__ __launch_bounds__(256) void ll_main4_kernel(
    const float4* __restrict__ xT4,
    const float* __restrict__ wgt,
    const float* __restrict__ bias,
    const int* __restrict__ cols,
    const int* __restrict__ row_ptr,
    float* __restrict__ out, int n_out) {
  __shared__ float tile[32][33];
  int tid = threadIdx.x;
  int g = tid >> 3;
  int l = tid & 7;
  int jb = blockIdx.x * 32;
  int j = jb + g;
  float ax = 0.f, ay = 0.f, az = 0.f, aw = 0.f;
  if (j < n_out) {
    int s = row_ptr[j];
    int e = row_ptr[j + 1];
    for (int base = s; base < e; base += 4) {
      int last = e - 1;
      int i1 = min(base + 1, last), i2 = min(base + 2, last), i3 = min(base + 3, last);
      int c0 = cols[base], c1 = cols[i1], c2 = cols[i2], c3 = cols[i3];
      float w0 = wgt[base];
      float w1 = (base + 1 <= last) ? wgt[i1] : 0.f;
      float w2 = (base + 2 <= last) ? wgt[i2] : 0.f;
      float w3 = (base + 3 <= last) ? wgt[i3] : 0.f;
      float4 x0 = xT4[(size_t)c0 * 8 + l];
      float4 x1 = xT4[(size_t)c1 * 8 + l];
      float4 x2 = xT4[(size_t)c2 * 8 + l];
      float4 x3 = xT4[(size_t)c3 * 8 + l];
      ax = fmaf(w0, x0.x, ax); ay = fmaf(w0, x0.y, ay);
      az = fmaf(w0, x0.z, az); aw = fmaf(w0, x0.w, aw);
      ax = fmaf(w1, x1.x, ax); ay = fmaf(w1, x1.y, ay);
      az = fmaf(w1, x1.z, az); aw = fmaf(w1, x1.w, aw);
      ax = fmaf(w2, x2.x, ax); ay = fmaf(w2, x2.y, ay);
      az = fmaf(w2, x2.z, az); aw = fmaf(w2, x2.w, aw);
      ax = fmaf(w3, x3.x, ax); ay = fmaf(w3, x3.y, ay);
      az = fmaf(w3, x3.z, az); aw = fmaf(w3, x3.w, aw);
    }
  }
  tile[l * 4 + 0][g] = ax;
  tile[l * 4 + 1][g] = ay;
  tile[l * 4 + 2][g] = az;
  tile[l * 4 + 3][g] = aw;
  __syncthreads();
  for (int idx = tid; idx < 32 * 32; idx += 256) {
    int bb = idx >> 5, jl = idx & 31;
    int jj = jb + jl;
    if (jj < n_out) out[(size_t)bb * n_out + jj] = tile[bb][jl] + bias[jj];
  }
}

__global__ __launch_bounds__(256) void ll_naive_kernel(
    const float* __restrict__ x,
    const float* __restrict__ wgt,
    const float* __restrict__ bias,
    const int* __restrict__ rows,
    const int* __restrict__ cols,
    float* __restrict__ out,
    int n_in, int n_out, int nnz, int B) {
  int idx = blockIdx.x * blockDim.x + threadIdx.x;
  if (idx >= n_out * B) return;
  int j = idx % n_out;
  int b = idx / n_out;
  int lo = 0, hi = nnz;
  while (lo < hi) { int m = (lo + hi) >> 1; if (rows[m] < j) lo = m + 1; else hi = m; }
  int s = lo;
  hi = nnz;
  while (lo < hi) { int m = (lo + hi) >> 1; if (rows[m] <= j) lo = m + 1; else hi = m; }
  int e = lo;
  float acc = 0.0f;
  for (int t = s; t < e; ++t)
    acc = fmaf(wgt[t], x[(size_t)b * n_in + cols[t]], acc);
  out[(size_t)b * n_out + j] = acc + bias[j];
}

extern "C" void kernel_launch(void* const* d_in, const int* in_sizes, int n_in_arrays,
                              void* d_out, int out_size, void* d_ws, size_t ws_size,
                              hipStream_t stream) {
  const float* x    = (const float*)d_in[0];
  const float* wgt  = (const float*)d_in[1];
  const float* bias = (const float*)d_in[2];
  const int*   rows = (const int*)d_in[3];
  const int*   cols = (const int*)d_in[4];
  float* out = (float*)d_out;

  const int nnz   = in_sizes[1];
  const int n_out = in_sizes[2];
  const int B     = out_size / n_out;           // 32
  const int n_in  = in_sizes[0] / B;            // 65536

  const size_t xTb_bytes = (size_t)n_in * 32 * 2;              // bf16 table
  const size_t xT_bytes  = (size_t)n_in * 32 * sizeof(float);  // fp32 table
  const size_t rp_bytes  = (size_t)(n_out + 1) * sizeof(int);

  if (B == 32 && ws_size >= xTb_bytes + rp_bytes) {
    u32* xTb = (u32*)d_ws;
    int* row_ptr = (int*)((char*)d_ws + xTb_bytes);
    int tblocks = (n_in + 63) / 64;
    int eblocks = (nnz + 255) / 256;
    prep_kernel<<<tblocks + eblocks, 256, 0, stream>>>(
        x, xTb, rows, row_ptr, n_in, n_out, nnz, tblocks);
    ll_main_bf16_kernel<<<(n_out + 63) / 64, 512, 0, stream>>>(
        (const uint4*)xTb, wgt, (const float4*)bias, cols, row_ptr,
        (float4*)out, n_out);
  } else if (B == 32 && ws_size >= xT_bytes + rp_bytes) {
    float* xT = (float*)d_ws;
    int* row_ptr = (int*)((char*)d_ws + xT_bytes);
    transpose_x_kernel<<<(n_in + 63) / 64, 256, 0, stream>>>(x, xT, n_in);
    build_rowptr_bs_kernel<<<(n_out + 256) / 256, 256, 0, stream>>>(rows, row_ptr, nnz, n_out);
    ll_main4_kernel<<<(n_out + 31) / 32, 256, 0, stream>>>(
        (const float4*)xT, wgt, bias, cols, row_ptr, out, n_out);
  } else {
    int total = n_out * B;
    ll_naive_kernel<<<(total + 255) / 256, 256, 0, stream>>>(
        x, wgt, bias, rows, cols, out, n_in, n_out, nnz, B);
  }
}